// Round 1
// baseline (2524.409 us; speedup 1.0000x reference)
//
#include <hip/hip_runtime.h>
#include <math.h>

static constexpr int NN = 100000;   // nodes
static constexpr int NE = 1600000;  // edges
static constexpr float BN_EPS = 1e-5f;

// ---------------- utility ----------------
__global__ void zero_f32(float* __restrict__ p, int n) {
    int i = blockIdx.x * blockDim.x + threadIdx.x;
    if (i < n) p[i] = 0.0f;
}

__global__ void deg_count(const int* __restrict__ dst, float* __restrict__ deg, int e) {
    int i = blockIdx.x * blockDim.x + threadIdx.x;
    if (i < e) atomicAdd(&deg[dst[i]], 1.0f);
}

__global__ void make_dinv(float* __restrict__ deg, int n) {
    int i = blockIdx.x * blockDim.x + threadIdx.x;
    if (i < n) deg[i] = rsqrtf(deg[i] + 1.0f);
}

// ---------------- GEMM: hw = h @ W ; agg = hw * dinv^2 (self-loop init) ----------------
// W is [FIN, FOUT] row-major. 16 rows per block, 256 threads.
template<int FIN, int FOUT>
__global__ __launch_bounds__(256) void gemm_self(
    const float* __restrict__ h, const float* __restrict__ W,
    const float* __restrict__ dinv, float* __restrict__ hw,
    float* __restrict__ agg, int n)
{
    constexpr int RB = 16;                 // rows per block
    constexpr int RSLOTS = 256 / FOUT;     // row slots across threads
    constexpr int RPT = RB / RSLOTS;       // rows per thread
    __shared__ float Ws[FIN * FOUT];
    __shared__ float hs[RB * FIN];

    const int tid = threadIdx.x;
    for (int i = tid; i < FIN * FOUT; i += 256) Ws[i] = W[i];

    const int row0 = blockIdx.x * RB;
    for (int i = tid; i < RB * FIN; i += 256) {
        int r = i / FIN, c = i % FIN;
        int g = row0 + r;
        hs[i] = (g < n) ? h[(size_t)g * FIN + c] : 0.0f;
    }
    __syncthreads();

    const int col = tid % FOUT;
    const int rs  = tid / FOUT;

    float acc[RPT];
#pragma unroll
    for (int r = 0; r < RPT; ++r) acc[r] = 0.0f;

#pragma unroll 8
    for (int k = 0; k < FIN; ++k) {
        float w = Ws[k * FOUT + col];
#pragma unroll
        for (int r = 0; r < RPT; ++r)
            acc[r] += hs[(rs * RPT + r) * FIN + k] * w;
    }

#pragma unroll
    for (int r = 0; r < RPT; ++r) {
        int g = row0 + rs * RPT + r;
        if (g < n) {
            float di = dinv[g];
            float v  = acc[r];
            hw [(size_t)g * FOUT + col] = v;
            agg[(size_t)g * FOUT + col] = v * (di * di);
        }
    }
}

// ---------------- edge scatter: agg[dst] += hw[src] * dinv[src]*dinv[dst] ----------------
template<int F>
__global__ __launch_bounds__(256) void edge_scatter(
    const int* __restrict__ src, const int* __restrict__ dst,
    const float* __restrict__ dinv, const float* __restrict__ hw,
    float* __restrict__ agg, int e)
{
    constexpr int C4 = F / 4;              // float4 chunks per edge
    int t  = blockIdx.x * 256 + threadIdx.x;
    int ed = t / C4;
    if (ed >= e) return;
    int c  = t % C4;
    int s  = src[ed], d = dst[ed];
    float coef = dinv[s] * dinv[d];
    float4 v = *reinterpret_cast<const float4*>(hw + (size_t)s * F + c * 4);
    float* o = agg + (size_t)d * F + c * 4;
    atomicAdd(o + 0, v.x * coef);
    atomicAdd(o + 1, v.y * coef);
    atomicAdd(o + 2, v.z * coef);
    atomicAdd(o + 3, v.w * coef);
}

// ---------------- fused bias + BN(eval) + ReLU, in place ----------------
template<int F>
__global__ __launch_bounds__(256) void bias_bn_relu(
    float* __restrict__ h, const float* __restrict__ b,
    const float* __restrict__ g, const float* __restrict__ be,
    const float* __restrict__ m, const float* __restrict__ v, int n)
{
    constexpr int C4 = F / 4;
    int i = blockIdx.x * 256 + threadIdx.x;
    if (i >= n * C4) return;
    int c = i % C4;
    float4 x  = reinterpret_cast<float4*>(h)[i];
    float4 bb = reinterpret_cast<const float4*>(b )[c];
    float4 gg = reinterpret_cast<const float4*>(g )[c];
    float4 ee = reinterpret_cast<const float4*>(be)[c];
    float4 mm = reinterpret_cast<const float4*>(m )[c];
    float4 vv = reinterpret_cast<const float4*>(v )[c];
    float4 y;
    y.x = fmaxf(gg.x * (x.x + bb.x - mm.x) * rsqrtf(vv.x + BN_EPS) + ee.x, 0.0f);
    y.y = fmaxf(gg.y * (x.y + bb.y - mm.y) * rsqrtf(vv.y + BN_EPS) + ee.y, 0.0f);
    y.z = fmaxf(gg.z * (x.z + bb.z - mm.z) * rsqrtf(vv.z + BN_EPS) + ee.z, 0.0f);
    y.w = fmaxf(gg.w * (x.w + bb.w - mm.w) * rsqrtf(vv.w + BN_EPS) + ee.w, 0.0f);
    reinterpret_cast<float4*>(h)[i] = y;
}

// ---------------- final FC(16->8) + sigmoid ----------------
__global__ __launch_bounds__(256) void fc_sigmoid(
    const float* __restrict__ h, const float* __restrict__ W,
    const float* __restrict__ b, float* __restrict__ out, int n)
{
    __shared__ float Ws[16 * 8];
    __shared__ float bs[8];
    int tid = threadIdx.x;
    if (tid < 128) Ws[tid] = W[tid];
    if (tid < 8)   bs[tid] = b[tid];
    __syncthreads();

    int node = blockIdx.x * 256 + tid;
    if (node >= n) return;

    float hr[16];
    const float4* hp = reinterpret_cast<const float4*>(h + (size_t)node * 16);
#pragma unroll
    for (int q = 0; q < 4; ++q) {
        float4 t4 = hp[q];
        hr[q*4+0] = t4.x; hr[q*4+1] = t4.y; hr[q*4+2] = t4.z; hr[q*4+3] = t4.w;
    }
    float o[8];
#pragma unroll
    for (int c = 0; c < 8; ++c) o[c] = bs[c];
#pragma unroll
    for (int k = 0; k < 16; ++k) {
#pragma unroll
        for (int c = 0; c < 8; ++c) o[c] += hr[k] * Ws[k * 8 + c];
    }
    float4 o0, o1;
    o0.x = 1.0f / (1.0f + expf(-o[0]));
    o0.y = 1.0f / (1.0f + expf(-o[1]));
    o0.z = 1.0f / (1.0f + expf(-o[2]));
    o0.w = 1.0f / (1.0f + expf(-o[3]));
    o1.x = 1.0f / (1.0f + expf(-o[4]));
    o1.y = 1.0f / (1.0f + expf(-o[5]));
    o1.z = 1.0f / (1.0f + expf(-o[6]));
    o1.w = 1.0f / (1.0f + expf(-o[7]));
    float4* op = reinterpret_cast<float4*>(out + (size_t)node * 8);
    op[0] = o0;
    op[1] = o1;
}

// ---------------- launch ----------------
extern "C" void kernel_launch(void* const* d_in, const int* in_sizes, int n_in,
                              void* d_out, int out_size, void* d_ws, size_t ws_size,
                              hipStream_t stream) {
    const float* x   = (const float*)d_in[0];
    const int*   ei  = (const int*)  d_in[1];   // [2, E]: src row then dst row
    const float* W1  = (const float*)d_in[2];
    const float* b1  = (const float*)d_in[3];
    const float* g1  = (const float*)d_in[4];
    const float* be1 = (const float*)d_in[5];
    const float* m1  = (const float*)d_in[6];
    const float* v1  = (const float*)d_in[7];
    const float* W2  = (const float*)d_in[8];
    const float* b2  = (const float*)d_in[9];
    const float* g2  = (const float*)d_in[10];
    const float* be2 = (const float*)d_in[11];
    const float* m2  = (const float*)d_in[12];
    const float* v2  = (const float*)d_in[13];
    const float* W3  = (const float*)d_in[14];
    const float* b3  = (const float*)d_in[15];
    const float* g3  = (const float*)d_in[16];
    const float* be3 = (const float*)d_in[17];
    const float* m3  = (const float*)d_in[18];
    const float* v3  = (const float*)d_in[19];
    const float* fcW = (const float*)d_in[20];
    const float* fcb = (const float*)d_in[21];
    float* out = (float*)d_out;

    const int* src = ei;
    const int* dst = ei + NE;

    char* w = (char*)d_ws;
    float* dinv = (float*)w;                                   // N floats (deg -> dinv)
    float* A = (float*)(w + (1 << 20));                        // N*64 floats
    float* B = (float*)(w + (1 << 20) + (size_t)NN * 64 * 4);  // N*64 floats

    float* hw1  = A;
    float* agg1 = B;               // becomes h1 in place
    float* hw2  = A;
    float* agg2 = A + (size_t)NN * 32;   // becomes h2 in place
    float* hw3  = B;
    float* agg3 = B + (size_t)NN * 16;   // becomes h3 in place

    // degree -> dinv
    zero_f32<<<(NN + 255) / 256, 256, 0, stream>>>(dinv, NN);
    deg_count<<<(NE + 255) / 256, 256, 0, stream>>>(dst, dinv, NE);
    make_dinv<<<(NN + 255) / 256, 256, 0, stream>>>(dinv, NN);

    // layer 1: 128 -> 64
    gemm_self<128, 64><<<(NN + 15) / 16, 256, 0, stream>>>(x, W1, dinv, hw1, agg1, NN);
    edge_scatter<64><<<(NE * 16 + 255) / 256, 256, 0, stream>>>(src, dst, dinv, hw1, agg1, NE);
    bias_bn_relu<64><<<(NN * 16 + 255) / 256, 256, 0, stream>>>(agg1, b1, g1, be1, m1, v1, NN);

    // layer 2: 64 -> 32
    gemm_self<64, 32><<<(NN + 15) / 16, 256, 0, stream>>>(agg1, W2, dinv, hw2, agg2, NN);
    edge_scatter<32><<<(NE * 8 + 255) / 256, 256, 0, stream>>>(src, dst, dinv, hw2, agg2, NE);
    bias_bn_relu<32><<<(NN * 8 + 255) / 256, 256, 0, stream>>>(agg2, b2, g2, be2, m2, v2, NN);

    // layer 3: 32 -> 16
    gemm_self<32, 16><<<(NN + 15) / 16, 256, 0, stream>>>(agg2, W3, dinv, hw3, agg3, NN);
    edge_scatter<16><<<(NE * 4 + 255) / 256, 256, 0, stream>>>(src, dst, dinv, hw3, agg3, NE);
    bias_bn_relu<16><<<(NN * 4 + 255) / 256, 256, 0, stream>>>(agg3, b3, g3, be3, m3, v3, NN);

    // FC + sigmoid
    fc_sigmoid<<<(NN + 255) / 256, 256, 0, stream>>>(agg3, fcW, fcb, out, NN);
}

// Round 2
// 439.171 us; speedup vs baseline: 5.7481x; 5.7481x over previous
//
#include <hip/hip_runtime.h>
#include <math.h>

static constexpr int NN = 100000;   // nodes
static constexpr int NE = 1600000;  // edges
static constexpr float BN_EPS = 1e-5f;

// ---------------- utility ----------------
__global__ void zero_i32(int* __restrict__ p, int n) {
    int i = blockIdx.x * blockDim.x + threadIdx.x;
    if (i < n) p[i] = 0;
}

__global__ void hist_dst(const int* __restrict__ dst, int* __restrict__ cnt, int e) {
    int i = blockIdx.x * blockDim.x + threadIdx.x;
    if (i < e) atomicAdd(&cnt[dst[i]], 1);
}

__global__ void make_dinv(const int* __restrict__ cnt, float* __restrict__ dinv, int n) {
    int i = blockIdx.x * blockDim.x + threadIdx.x;
    if (i < n) dinv[i] = rsqrtf((float)cnt[i] + 1.0f);
}

// ---------------- exclusive scan of cnt[N] -> off[N] (3-kernel, 1024 elems/block) ----
__global__ __launch_bounds__(256) void scan1(const int* __restrict__ cnt, int* __restrict__ off,
                                             int* __restrict__ bsum, int n) {
    __shared__ int s[256];
    int base = blockIdx.x * 1024;
    int t = threadIdx.x;
    int v[4]; int sum = 0;
#pragma unroll
    for (int k = 0; k < 4; ++k) {
        int i = base + t * 4 + k;
        v[k] = (i < n) ? cnt[i] : 0;
        sum += v[k];
    }
    s[t] = sum;
    __syncthreads();
    for (int d = 1; d < 256; d <<= 1) {
        int x = (t >= d) ? s[t - d] : 0;
        __syncthreads();
        s[t] += x;
        __syncthreads();
    }
    int excl = (t == 0) ? 0 : s[t - 1];
    if (t == 255) bsum[blockIdx.x] = s[255];
#pragma unroll
    for (int k = 0; k < 4; ++k) {
        int i = base + t * 4 + k;
        if (i < n) off[i] = excl;
        excl += v[k];
    }
}

__global__ __launch_bounds__(128) void scan2(int* __restrict__ bsum, int nb) {
    __shared__ int s[128];
    int t = threadIdx.x;
    s[t] = (t < nb) ? bsum[t] : 0;
    __syncthreads();
    for (int d = 1; d < 128; d <<= 1) {
        int x = (t >= d) ? s[t - d] : 0;
        __syncthreads();
        s[t] += x;
        __syncthreads();
    }
    if (t < nb) bsum[t] = (t == 0) ? 0 : s[t - 1];
}

__global__ __launch_bounds__(256) void scan3(int* __restrict__ off, int* __restrict__ cursor,
                                             const int* __restrict__ bsum, int n) {
    int base = blockIdx.x * 1024;
    int add = bsum[blockIdx.x];
    for (int k = threadIdx.x; k < 1024; k += 256) {
        int i = base + k;
        if (i < n) { int o = off[i] + add; off[i] = o; cursor[i] = o; }
    }
}

// ---------------- CSR placement: epack[pos] = {src, coef} ----------------
__global__ __launch_bounds__(256) void build_csr(
    const int* __restrict__ src, const int* __restrict__ dst,
    const float* __restrict__ dinv, int* __restrict__ cursor,
    int2* __restrict__ epack, int e)
{
    int i = blockIdx.x * 256 + threadIdx.x;
    if (i >= e) return;
    int s = src[i], d = dst[i];
    float c = dinv[s] * dinv[d];
    int pos = atomicAdd(&cursor[d], 1);
    int2 p; p.x = s; p.y = __float_as_int(c);
    epack[pos] = p;
}

// ---------------- GEMM: hw = h @ W ----------------
// W is [FIN, FOUT] row-major. 16 rows per block, 256 threads.
template<int FIN, int FOUT>
__global__ __launch_bounds__(256) void gemm_rows(
    const float* __restrict__ h, const float* __restrict__ W,
    float* __restrict__ hw, int n)
{
    constexpr int RB = 16;
    constexpr int RSLOTS = 256 / FOUT;
    constexpr int RPT = RB / RSLOTS;
    __shared__ float Ws[FIN * FOUT];
    __shared__ float hs[RB * FIN];

    const int tid = threadIdx.x;
    for (int i = tid; i < FIN * FOUT; i += 256) Ws[i] = W[i];

    const int row0 = blockIdx.x * RB;
    for (int i = tid; i < RB * FIN; i += 256) {
        int r = i / FIN, c = i % FIN;
        int g = row0 + r;
        hs[i] = (g < n) ? h[(size_t)g * FIN + c] : 0.0f;
    }
    __syncthreads();

    const int col = tid % FOUT;
    const int rs  = tid / FOUT;

    float acc[RPT];
#pragma unroll
    for (int r = 0; r < RPT; ++r) acc[r] = 0.0f;

#pragma unroll 8
    for (int k = 0; k < FIN; ++k) {
        float w = Ws[k * FOUT + col];
#pragma unroll
        for (int r = 0; r < RPT; ++r)
            acc[r] += hs[(rs * RPT + r) * FIN + k] * w;
    }

#pragma unroll
    for (int r = 0; r < RPT; ++r) {
        int g = row0 + rs * RPT + r;
        if (g < n) hw[(size_t)g * FOUT + col] = acc[r];
    }
}

// ---------------- gather + self-loop + bias + BN + ReLU ----------------
// One F-lane group per destination node; coalesced hw[src] row reads.
template<int F>
__global__ __launch_bounds__(256) void gather_bn_relu(
    const int* __restrict__ off, const int* __restrict__ cnt,
    const int2* __restrict__ epack, const float* __restrict__ dinv,
    const float* __restrict__ hw, const float* __restrict__ bias,
    const float* __restrict__ g, const float* __restrict__ be,
    const float* __restrict__ m, const float* __restrict__ v,
    float* __restrict__ hout, int n)
{
    int node = blockIdx.x * (256 / F) + threadIdx.x / F;
    if (node >= n) return;
    int col = threadIdx.x % F;

    float di  = dinv[node];
    float acc = hw[(size_t)node * F + col] * (di * di);   // self-loop

    int beg = off[node];
    int num = cnt[node];
    int j = 0;
    for (; j + 1 < num; j += 2) {
        int2 p0 = epack[beg + j];
        int2 p1 = epack[beg + j + 1];
        float h0 = hw[(size_t)p0.x * F + col];
        float h1 = hw[(size_t)p1.x * F + col];
        acc += h0 * __int_as_float(p0.y);
        acc += h1 * __int_as_float(p1.y);
    }
    if (j < num) {
        int2 p = epack[beg + j];
        acc += hw[(size_t)p.x * F + col] * __int_as_float(p.y);
    }

    float y = g[col] * (acc + bias[col] - m[col]) * rsqrtf(v[col] + BN_EPS) + be[col];
    hout[(size_t)node * F + col] = fmaxf(y, 0.0f);
}

// ---------------- final FC(16->8) + sigmoid ----------------
__global__ __launch_bounds__(256) void fc_sigmoid(
    const float* __restrict__ h, const float* __restrict__ W,
    const float* __restrict__ b, float* __restrict__ out, int n)
{
    __shared__ float Ws[16 * 8];
    __shared__ float bs[8];
    int tid = threadIdx.x;
    if (tid < 128) Ws[tid] = W[tid];
    if (tid < 8)   bs[tid] = b[tid];
    __syncthreads();

    int node = blockIdx.x * 256 + tid;
    if (node >= n) return;

    float hr[16];
    const float4* hp = reinterpret_cast<const float4*>(h + (size_t)node * 16);
#pragma unroll
    for (int q = 0; q < 4; ++q) {
        float4 t4 = hp[q];
        hr[q*4+0] = t4.x; hr[q*4+1] = t4.y; hr[q*4+2] = t4.z; hr[q*4+3] = t4.w;
    }
    float o[8];
#pragma unroll
    for (int c = 0; c < 8; ++c) o[c] = bs[c];
#pragma unroll
    for (int k = 0; k < 16; ++k) {
#pragma unroll
        for (int c = 0; c < 8; ++c) o[c] += hr[k] * Ws[k * 8 + c];
    }
    float4 o0, o1;
    o0.x = 1.0f / (1.0f + expf(-o[0]));
    o0.y = 1.0f / (1.0f + expf(-o[1]));
    o0.z = 1.0f / (1.0f + expf(-o[2]));
    o0.w = 1.0f / (1.0f + expf(-o[3]));
    o1.x = 1.0f / (1.0f + expf(-o[4]));
    o1.y = 1.0f / (1.0f + expf(-o[5]));
    o1.z = 1.0f / (1.0f + expf(-o[6]));
    o1.w = 1.0f / (1.0f + expf(-o[7]));
    float4* op = reinterpret_cast<float4*>(out + (size_t)node * 8);
    op[0] = o0;
    op[1] = o1;
}

// ---------------- launch ----------------
extern "C" void kernel_launch(void* const* d_in, const int* in_sizes, int n_in,
                              void* d_out, int out_size, void* d_ws, size_t ws_size,
                              hipStream_t stream) {
    const float* x   = (const float*)d_in[0];
    const int*   ei  = (const int*)  d_in[1];   // [2, E]: src row then dst row
    const float* W1  = (const float*)d_in[2];
    const float* b1  = (const float*)d_in[3];
    const float* g1  = (const float*)d_in[4];
    const float* be1 = (const float*)d_in[5];
    const float* m1  = (const float*)d_in[6];
    const float* v1  = (const float*)d_in[7];
    const float* W2  = (const float*)d_in[8];
    const float* b2  = (const float*)d_in[9];
    const float* g2  = (const float*)d_in[10];
    const float* be2 = (const float*)d_in[11];
    const float* m2  = (const float*)d_in[12];
    const float* v2  = (const float*)d_in[13];
    const float* W3  = (const float*)d_in[14];
    const float* b3  = (const float*)d_in[15];
    const float* g3  = (const float*)d_in[16];
    const float* be3 = (const float*)d_in[17];
    const float* m3  = (const float*)d_in[18];
    const float* v3  = (const float*)d_in[19];
    const float* fcW = (const float*)d_in[20];
    const float* fcb = (const float*)d_in[21];
    float* out = (float*)d_out;

    const int* src = ei;
    const int* dst = ei + NE;

    char* w = (char*)d_ws;
    float* dinv   = (float*)(w + 0);                 // N floats
    int*   cnt    = (int*)  (w + (512 << 10));       // N ints
    int*   off    = (int*)  (w + (1024 << 10));      // N ints
    int*   cursor = (int*)  (w + (1536 << 10));      // N ints
    int*   bsum   = (int*)  (w + (2048 << 10));      // 128 ints
    int2*  epack  = (int2*) (w + (2112 << 10));      // E int2 = 12.8 MB
    float* A      = (float*)(w + (16u << 20));       // N*64 floats = 25.6 MB
    float* B      = (float*)(w + (42u << 20));       // N*64 floats = 25.6 MB

    float* hw1 = A;
    float* h1  = B;
    float* hw2 = A;
    float* h2  = A + (size_t)NN * 32;
    float* hw3 = B;
    float* h3  = B + (size_t)NN * 16;

    const int NB = (NN + 1023) / 1024;   // 98 scan blocks

    // degree histogram -> dinv, CSR offsets, placement
    zero_i32<<<(NN + 255) / 256, 256, 0, stream>>>(cnt, NN);
    hist_dst<<<(NE + 255) / 256, 256, 0, stream>>>(dst, cnt, NE);
    make_dinv<<<(NN + 255) / 256, 256, 0, stream>>>(cnt, dinv, NN);
    scan1<<<NB, 256, 0, stream>>>(cnt, off, bsum, NN);
    scan2<<<1, 128, 0, stream>>>(bsum, NB);
    scan3<<<NB, 256, 0, stream>>>(off, cursor, bsum, NN);
    build_csr<<<(NE + 255) / 256, 256, 0, stream>>>(src, dst, dinv, cursor, epack, NE);

    // layer 1: 128 -> 64
    gemm_rows<128, 64><<<(NN + 15) / 16, 256, 0, stream>>>(x, W1, hw1, NN);
    gather_bn_relu<64><<<(NN * 64 + 255) / 256, 256, 0, stream>>>(
        off, cnt, epack, dinv, hw1, b1, g1, be1, m1, v1, h1, NN);

    // layer 2: 64 -> 32
    gemm_rows<64, 32><<<(NN + 15) / 16, 256, 0, stream>>>(h1, W2, hw2, NN);
    gather_bn_relu<32><<<(NN * 32 + 255) / 256, 256, 0, stream>>>(
        off, cnt, epack, dinv, hw2, b2, g2, be2, m2, v2, h2, NN);

    // layer 3: 32 -> 16
    gemm_rows<32, 16><<<(NN + 15) / 16, 256, 0, stream>>>(h2, W3, hw3, NN);
    gather_bn_relu<16><<<(NN * 16 + 255) / 256, 256, 0, stream>>>(
        off, cnt, epack, dinv, hw3, b3, g3, be3, m3, v3, h3, NN);

    // FC + sigmoid
    fc_sigmoid<<<(NN + 255) / 256, 256, 0, stream>>>(h3, fcW, fcb, out, NN);
}

// Round 3
// 424.989 us; speedup vs baseline: 5.9399x; 1.0334x over previous
//
#include <hip/hip_runtime.h>
#include <math.h>

static constexpr int NN = 100000;   // nodes
static constexpr int NE = 1600000;  // edges
static constexpr float BN_EPS = 1e-5f;

// bf16 helpers (RNE pack, truncation-style unpack)
__device__ __forceinline__ unsigned short f2bf(float f) {
    unsigned int u = __float_as_uint(f);
    u += 0x7fffu + ((u >> 16) & 1u);
    return (unsigned short)(u >> 16);
}
__device__ __forceinline__ float bf2f(unsigned short b) {
    return __uint_as_float(((unsigned int)b) << 16);
}

// ---------------- utility ----------------
__global__ void zero_i32(int* __restrict__ p, int n) {
    int i = blockIdx.x * blockDim.x + threadIdx.x;
    if (i < n) p[i] = 0;
}

__global__ void hist_dst(const int* __restrict__ dst, int* __restrict__ cnt, int e) {
    int i = blockIdx.x * blockDim.x + threadIdx.x;
    if (i < e) atomicAdd(&cnt[dst[i]], 1);
}

__global__ void make_dinv(const int* __restrict__ cnt, float* __restrict__ dinv, int n) {
    int i = blockIdx.x * blockDim.x + threadIdx.x;
    if (i < n) dinv[i] = rsqrtf((float)cnt[i] + 1.0f);
}

// ---------------- exclusive scan of cnt[N] -> off[N] ----------------
__global__ __launch_bounds__(256) void scan1(const int* __restrict__ cnt, int* __restrict__ off,
                                             int* __restrict__ bsum, int n) {
    __shared__ int s[256];
    int base = blockIdx.x * 1024;
    int t = threadIdx.x;
    int v[4]; int sum = 0;
#pragma unroll
    for (int k = 0; k < 4; ++k) {
        int i = base + t * 4 + k;
        v[k] = (i < n) ? cnt[i] : 0;
        sum += v[k];
    }
    s[t] = sum;
    __syncthreads();
    for (int d = 1; d < 256; d <<= 1) {
        int x = (t >= d) ? s[t - d] : 0;
        __syncthreads();
        s[t] += x;
        __syncthreads();
    }
    int excl = (t == 0) ? 0 : s[t - 1];
    if (t == 255) bsum[blockIdx.x] = s[255];
#pragma unroll
    for (int k = 0; k < 4; ++k) {
        int i = base + t * 4 + k;
        if (i < n) off[i] = excl;
        excl += v[k];
    }
}

__global__ __launch_bounds__(128) void scan2(int* __restrict__ bsum, int nb) {
    __shared__ int s[128];
    int t = threadIdx.x;
    s[t] = (t < nb) ? bsum[t] : 0;
    __syncthreads();
    for (int d = 1; d < 128; d <<= 1) {
        int x = (t >= d) ? s[t - d] : 0;
        __syncthreads();
        s[t] += x;
        __syncthreads();
    }
    if (t < nb) bsum[t] = (t == 0) ? 0 : s[t - 1];
}

__global__ __launch_bounds__(256) void scan3(int* __restrict__ off, int* __restrict__ cursor,
                                             const int* __restrict__ bsum, int n) {
    int base = blockIdx.x * 1024;
    int add = bsum[blockIdx.x];
    for (int k = threadIdx.x; k < 1024; k += 256) {
        int i = base + k;
        if (i < n) { int o = off[i] + add; off[i] = o; cursor[i] = o; }
    }
}

// ---------------- CSR placement: esrc[pos] = src ----------------
__global__ __launch_bounds__(256) void build_csr(
    const int* __restrict__ src, const int* __restrict__ dst,
    int* __restrict__ cursor, int* __restrict__ esrc, int e)
{
    int i = blockIdx.x * 256 + threadIdx.x;
    if (i >= e) return;
    int s = src[i], d = dst[i];
    int pos = atomicAdd(&cursor[d], 1);
    esrc[pos] = s;
}

// ---------------- GEMM: hw' = (h @ W) * dinv, stored bf16 ----------------
// W is [FIN, FOUT] row-major. 16 rows per block, 256 threads.
template<int FIN, int FOUT>
__global__ __launch_bounds__(256) void gemm_rows(
    const float* __restrict__ h, const float* __restrict__ W,
    const float* __restrict__ dinv, unsigned short* __restrict__ hw, int n)
{
    constexpr int RB = 16;
    constexpr int RSLOTS = 256 / FOUT;
    constexpr int RPT = RB / RSLOTS;
    __shared__ float Ws[FIN * FOUT];
    __shared__ float hs[RB * FIN];

    const int tid = threadIdx.x;
    for (int i = tid; i < FIN * FOUT; i += 256) Ws[i] = W[i];

    const int row0 = blockIdx.x * RB;
    for (int i = tid; i < RB * FIN; i += 256) {
        int r = i / FIN, c = i % FIN;
        int g = row0 + r;
        hs[i] = (g < n) ? h[(size_t)g * FIN + c] : 0.0f;
    }
    __syncthreads();

    const int col = tid % FOUT;
    const int rs  = tid / FOUT;

    float acc[RPT];
#pragma unroll
    for (int r = 0; r < RPT; ++r) acc[r] = 0.0f;

#pragma unroll 8
    for (int k = 0; k < FIN; ++k) {
        float w = Ws[k * FOUT + col];
#pragma unroll
        for (int r = 0; r < RPT; ++r)
            acc[r] += hs[(rs * RPT + r) * FIN + k] * w;
    }

#pragma unroll
    for (int r = 0; r < RPT; ++r) {
        int g = row0 + rs * RPT + r;
        if (g < n) hw[(size_t)g * FOUT + col] = f2bf(acc[r] * dinv[g]);
    }
}

// ---------------- gather + self-loop + bias + BN + ReLU ----------------
// hw' rows are bf16, pre-scaled by dinv[src]. out = relu(A*(dinv_d*S + b - m) + be)
template<int F>
__global__ __launch_bounds__(256) void gather_bn_relu(
    const int* __restrict__ off, const int* __restrict__ cnt,
    const int* __restrict__ esrc, const float* __restrict__ dinv,
    const unsigned short* __restrict__ hw, const float* __restrict__ bias,
    const float* __restrict__ g, const float* __restrict__ be,
    const float* __restrict__ m, const float* __restrict__ v,
    float* __restrict__ hout, int n)
{
    int node = blockIdx.x * (256 / F) + threadIdx.x / F;
    if (node >= n) return;
    int col = threadIdx.x % F;

    float S = bf2f(hw[(size_t)node * F + col]);   // self-loop term (hw' = hw*dinv)

    int beg = off[node];
    int num = cnt[node];
    int j = 0;
    for (; j + 3 < num; j += 4) {
        int s0 = esrc[beg + j + 0];
        int s1 = esrc[beg + j + 1];
        int s2 = esrc[beg + j + 2];
        int s3 = esrc[beg + j + 3];
        float h0 = bf2f(hw[(size_t)s0 * F + col]);
        float h1 = bf2f(hw[(size_t)s1 * F + col]);
        float h2 = bf2f(hw[(size_t)s2 * F + col]);
        float h3 = bf2f(hw[(size_t)s3 * F + col]);
        S += h0 + h1 + h2 + h3;
    }
    for (; j < num; ++j) {
        int s = esrc[beg + j];
        S += bf2f(hw[(size_t)s * F + col]);
    }

    float A = g[col] * rsqrtf(v[col] + BN_EPS);
    float y = A * (dinv[node] * S + bias[col] - m[col]) + be[col];
    hout[(size_t)node * F + col] = fmaxf(y, 0.0f);
}

// ---------------- final FC(16->8) + sigmoid ----------------
__global__ __launch_bounds__(256) void fc_sigmoid(
    const float* __restrict__ h, const float* __restrict__ W,
    const float* __restrict__ b, float* __restrict__ out, int n)
{
    __shared__ float Ws[16 * 8];
    __shared__ float bs[8];
    int tid = threadIdx.x;
    if (tid < 128) Ws[tid] = W[tid];
    if (tid < 8)   bs[tid] = b[tid];
    __syncthreads();

    int node = blockIdx.x * 256 + tid;
    if (node >= n) return;

    float hr[16];
    const float4* hp = reinterpret_cast<const float4*>(h + (size_t)node * 16);
#pragma unroll
    for (int q = 0; q < 4; ++q) {
        float4 t4 = hp[q];
        hr[q*4+0] = t4.x; hr[q*4+1] = t4.y; hr[q*4+2] = t4.z; hr[q*4+3] = t4.w;
    }
    float o[8];
#pragma unroll
    for (int c = 0; c < 8; ++c) o[c] = bs[c];
#pragma unroll
    for (int k = 0; k < 16; ++k) {
#pragma unroll
        for (int c = 0; c < 8; ++c) o[c] += hr[k] * Ws[k * 8 + c];
    }
    float4 o0, o1;
    o0.x = 1.0f / (1.0f + expf(-o[0]));
    o0.y = 1.0f / (1.0f + expf(-o[1]));
    o0.z = 1.0f / (1.0f + expf(-o[2]));
    o0.w = 1.0f / (1.0f + expf(-o[3]));
    o1.x = 1.0f / (1.0f + expf(-o[4]));
    o1.y = 1.0f / (1.0f + expf(-o[5]));
    o1.z = 1.0f / (1.0f + expf(-o[6]));
    o1.w = 1.0f / (1.0f + expf(-o[7]));
    float4* op = reinterpret_cast<float4*>(out + (size_t)node * 8);
    op[0] = o0;
    op[1] = o1;
}

// ---------------- launch ----------------
extern "C" void kernel_launch(void* const* d_in, const int* in_sizes, int n_in,
                              void* d_out, int out_size, void* d_ws, size_t ws_size,
                              hipStream_t stream) {
    const float* x   = (const float*)d_in[0];
    const int*   ei  = (const int*)  d_in[1];   // [2, E]: src row then dst row
    const float* W1  = (const float*)d_in[2];
    const float* b1  = (const float*)d_in[3];
    const float* g1  = (const float*)d_in[4];
    const float* be1 = (const float*)d_in[5];
    const float* m1  = (const float*)d_in[6];
    const float* v1  = (const float*)d_in[7];
    const float* W2  = (const float*)d_in[8];
    const float* b2  = (const float*)d_in[9];
    const float* g2  = (const float*)d_in[10];
    const float* be2 = (const float*)d_in[11];
    const float* m2  = (const float*)d_in[12];
    const float* v2  = (const float*)d_in[13];
    const float* W3  = (const float*)d_in[14];
    const float* b3  = (const float*)d_in[15];
    const float* g3  = (const float*)d_in[16];
    const float* be3 = (const float*)d_in[17];
    const float* m3  = (const float*)d_in[18];
    const float* v3  = (const float*)d_in[19];
    const float* fcW = (const float*)d_in[20];
    const float* fcb = (const float*)d_in[21];
    float* out = (float*)d_out;

    const int* src = ei;
    const int* dst = ei + NE;

    char* w = (char*)d_ws;
    float* dinv   = (float*)(w + 0);                   // N f32
    int*   cnt    = (int*)  (w + (512 << 10));         // N i32
    int*   off    = (int*)  (w + (1024 << 10));        // N i32
    int*   cursor = (int*)  (w + (1536 << 10));        // N i32
    int*   bsum   = (int*)  (w + (2048 << 10));        // 128 i32
    int*   esrc   = (int*)  (w + (2112 << 10));        // E i32 = 6.4 MB
    unsigned short* hw = (unsigned short*)(w + (16u << 20)); // N*64 bf16 = 12.8 MB
    float* H      = (float*)(w + (30u << 20));         // N*64 f32 = 25.6 MB (h1/h2/h3 reuse)

    float* h1 = H;
    float* h2 = H;
    float* h3 = H;

    const int NB = (NN + 1023) / 1024;

    // degree histogram -> dinv, CSR offsets, placement
    zero_i32<<<(NN + 255) / 256, 256, 0, stream>>>(cnt, NN);
    hist_dst<<<(NE + 255) / 256, 256, 0, stream>>>(dst, cnt, NE);
    make_dinv<<<(NN + 255) / 256, 256, 0, stream>>>(cnt, dinv, NN);
    scan1<<<NB, 256, 0, stream>>>(cnt, off, bsum, NN);
    scan2<<<1, 128, 0, stream>>>(bsum, NB);
    scan3<<<NB, 256, 0, stream>>>(off, cursor, bsum, NN);
    build_csr<<<(NE + 255) / 256, 256, 0, stream>>>(src, dst, cursor, esrc, NE);

    // layer 1: 128 -> 64
    gemm_rows<128, 64><<<(NN + 15) / 16, 256, 0, stream>>>(x, W1, dinv, hw, NN);
    gather_bn_relu<64><<<(NN * 64 + 255) / 256, 256, 0, stream>>>(
        off, cnt, esrc, dinv, hw, b1, g1, be1, m1, v1, h1, NN);

    // layer 2: 64 -> 32
    gemm_rows<64, 32><<<(NN + 15) / 16, 256, 0, stream>>>(h1, W2, dinv, hw, NN);
    gather_bn_relu<32><<<(NN * 32 + 255) / 256, 256, 0, stream>>>(
        off, cnt, esrc, dinv, hw, b2, g2, be2, m2, v2, h2, NN);

    // layer 3: 32 -> 16
    gemm_rows<32, 16><<<(NN + 15) / 16, 256, 0, stream>>>(h2, W3, dinv, hw, NN);
    gather_bn_relu<16><<<(NN * 16 + 255) / 256, 256, 0, stream>>>(
        off, cnt, esrc, dinv, hw, b3, g3, be3, m3, v3, h3, NN);

    // FC + sigmoid
    fc_sigmoid<<<(NN + 255) / 256, 256, 0, stream>>>(h3, fcW, fcb, out, NN);
}

// Round 4
// 297.242 us; speedup vs baseline: 8.4928x; 1.4298x over previous
//
#include <hip/hip_runtime.h>
#include <math.h>

static constexpr int NN = 100000;   // nodes
static constexpr int NE = 1600000;  // edges
static constexpr float BN_EPS = 1e-5f;
static constexpr int K_BKT = (NN + 255) / 256;   // 391 coarse buckets (dst>>8)
static constexpr int CH = 8192;                  // edges per partition block

// bf16 helpers (RNE pack, truncation-style unpack)
__device__ __forceinline__ unsigned short f2bf(float f) {
    unsigned int u = __float_as_uint(f);
    u += 0x7fffu + ((u >> 16) & 1u);
    return (unsigned short)(u >> 16);
}
__device__ __forceinline__ float bf2f(unsigned short b) {
    return __uint_as_float(((unsigned int)b) << 16);
}

// ---------------- utility ----------------
__global__ void zero_i32(int* __restrict__ p, int n) {
    int i = blockIdx.x * blockDim.x + threadIdx.x;
    if (i < n) p[i] = 0;
}

// ---------------- coarse bucket histogram (LDS pre-aggregated) ----------------
__global__ __launch_bounds__(256) void bucket_hist(
    const int* __restrict__ dst, int* __restrict__ bhist, int e)
{
    __shared__ int h[K_BKT];
    for (int i = threadIdx.x; i < K_BKT; i += 256) h[i] = 0;
    __syncthreads();
    int stride = gridDim.x * 256;
    for (int i = blockIdx.x * 256 + threadIdx.x; i < e; i += stride)
        atomicAdd(&h[((unsigned)dst[i]) >> 8], 1);
    __syncthreads();
    for (int i = threadIdx.x; i < K_BKT; i += 256)
        if (h[i]) atomicAdd(&bhist[i], h[i]);
}

// ---------------- scan 391 bucket counts -> bases & cursors (1 block) --------
__global__ __launch_bounds__(256) void scan_buckets(
    const int* __restrict__ bhist, int* __restrict__ bbase, int* __restrict__ bcur)
{
    __shared__ int a[512];
    int tid = threadIdx.x;
    a[tid]       = (tid < K_BKT) ? bhist[tid] : 0;
    a[tid + 256] = (tid + 256 < K_BKT) ? bhist[tid + 256] : 0;
    __syncthreads();
    for (int d = 1; d < 512; d <<= 1) {
        int x0 = (tid >= d) ? a[tid - d] : 0;
        int i1 = tid + 256;
        int x1 = (i1 >= d) ? a[i1 - d] : 0;
        __syncthreads();
        a[tid] += x0;
        a[i1]  += x1;
        __syncthreads();
    }
    if (tid < K_BKT) {
        int ex = (tid == 0) ? 0 : a[tid - 1];
        bbase[tid] = ex; bcur[tid] = ex;
    }
    int i1 = tid + 256;
    if (i1 < K_BKT) {
        int ex = a[i1 - 1];
        bbase[i1] = ex; bcur[i1] = ex;
    }
}

// ---------------- partition: bucket-grouped staged writes (coalesced runs) ---
// staged[pos] = src | ((dst&255)<<24), grouped by bucket b = dst>>8.
__global__ __launch_bounds__(256) void partition_edges(
    const int* __restrict__ src, const int* __restrict__ dst,
    int* __restrict__ bcur, int* __restrict__ staged, int e)
{
    __shared__ int s_out[CH];       // 32 KB
    __shared__ int cntL[512];       // counts -> inclusive scan
    __shared__ int gbase[K_BKT];
    __shared__ int curL[K_BKT];

    int tid = threadIdx.x;
    int c0 = blockIdx.x * CH;
    int cend = min(c0 + CH, e);

    for (int i = tid; i < 512; i += 256) cntL[i] = 0;
    __syncthreads();

    // pass A: count per bucket
    for (int i = c0 + tid; i < cend; i += 256)
        atomicAdd(&cntL[((unsigned)dst[i]) >> 8], 1);
    __syncthreads();

    // reserve contiguous global runs (one atomic per non-empty bucket)
    for (int b = tid; b < K_BKT; b += 256) {
        int c = cntL[b];
        gbase[b] = (c > 0) ? atomicAdd(&bcur[b], c) : 0;
    }
    __syncthreads();

    // inclusive scan of cntL (512, 2 elems/thread Hillis-Steele)
    for (int d = 1; d < 512; d <<= 1) {
        int x0 = (tid >= d) ? cntL[tid - d] : 0;
        int i1 = tid + 256;
        int x1 = (i1 >= d) ? cntL[i1 - d] : 0;
        __syncthreads();
        cntL[tid] += x0;
        cntL[i1]  += x1;
        __syncthreads();
    }
    for (int b = tid; b < K_BKT; b += 256)
        curL[b] = (b == 0) ? 0 : cntL[b - 1];
    __syncthreads();

    // pass B: reorder into LDS grouped by bucket (re-read edges, L2-hot)
    for (int i = c0 + tid; i < cend; i += 256) {
        int s = src[i];
        int d = dst[i];
        int b = ((unsigned)d) >> 8;
        int r = atomicAdd(&curL[b], 1);
        s_out[r] = s | ((d & 255) << 24);
    }
    __syncthreads();

    // write out: each wave owns buckets strided; contiguous runs per bucket
    int wave = tid >> 6, lane = tid & 63;
    for (int b = wave; b < K_BKT; b += 4) {
        int lo = (b == 0) ? 0 : cntL[b - 1];
        int hi = cntL[b];
        int gb = gbase[b];
        for (int i = lo + lane; i < hi; i += 64)
            staged[gb + (i - lo)] = s_out[i];
    }
}

// ---------------- place: per-bucket CSR finalize (XCD-local writes) ----------
// Also produces off[], cnt[], dinv[] (replaces hist/scan/make_dinv).
__global__ __launch_bounds__(256) void place_edges(
    const int* __restrict__ bbase, const int* __restrict__ staged,
    int* __restrict__ esrc, int* __restrict__ off, int* __restrict__ cnt,
    float* __restrict__ dinv, int n, int e)
{
    __shared__ int cntL[256];
    __shared__ int scn[256];
    __shared__ int curL[256];
    int b = blockIdx.x;
    int tid = threadIdx.x;
    int node0 = b << 8;
    int nN = min(256, n - node0);
    int beg = bbase[b];
    int end = (b == (int)gridDim.x - 1) ? e : bbase[b + 1];

    cntL[tid] = 0;
    __syncthreads();
    for (int i = beg + tid; i < end; i += 256)
        atomicAdd(&cntL[((unsigned)staged[i]) >> 24], 1);
    __syncthreads();
    scn[tid] = cntL[tid];
    __syncthreads();
    for (int d = 1; d < 256; d <<= 1) {
        int x = (tid >= d) ? scn[tid - d] : 0;
        __syncthreads();
        scn[tid] += x;
        __syncthreads();
    }
    int lofs = (tid == 0) ? 0 : scn[tid - 1];
    if (tid < nN) {
        int node = node0 + tid;
        off[node] = beg + lofs;
        cnt[node] = cntL[tid];
        dinv[node] = rsqrtf((float)cntL[tid] + 1.0f);
    }
    curL[tid] = beg + lofs;
    __syncthreads();
    for (int i = beg + tid; i < end; i += 256) {
        int u = staged[i];
        int pos = atomicAdd(&curL[((unsigned)u) >> 24], 1);
        esrc[pos] = u & 0x00FFFFFF;
    }
}

// ---------------- GEMM: hw' = (h @ W) * dinv, stored bf16 ----------------
template<int FIN, int FOUT>
__global__ __launch_bounds__(256) void gemm_rows(
    const float* __restrict__ h, const float* __restrict__ W,
    const float* __restrict__ dinv, unsigned short* __restrict__ hw, int n)
{
    constexpr int RB = 16;
    constexpr int RSLOTS = 256 / FOUT;
    constexpr int RPT = RB / RSLOTS;
    __shared__ float Ws[FIN * FOUT];
    __shared__ float hs[RB * FIN];

    const int tid = threadIdx.x;
    for (int i = tid; i < FIN * FOUT; i += 256) Ws[i] = W[i];

    const int row0 = blockIdx.x * RB;
    for (int i = tid; i < RB * FIN; i += 256) {
        int r = i / FIN, c = i % FIN;
        int g = row0 + r;
        hs[i] = (g < n) ? h[(size_t)g * FIN + c] : 0.0f;
    }
    __syncthreads();

    const int col = tid % FOUT;
    const int rs  = tid / FOUT;

    float acc[RPT];
#pragma unroll
    for (int r = 0; r < RPT; ++r) acc[r] = 0.0f;

#pragma unroll 8
    for (int k = 0; k < FIN; ++k) {
        float w = Ws[k * FOUT + col];
#pragma unroll
        for (int r = 0; r < RPT; ++r)
            acc[r] += hs[(rs * RPT + r) * FIN + k] * w;
    }

#pragma unroll
    for (int r = 0; r < RPT; ++r) {
        int g = row0 + rs * RPT + r;
        if (g < n) hw[(size_t)g * FOUT + col] = f2bf(acc[r] * dinv[g]);
    }
}

// ---------------- gather + self-loop + bias + BN + ReLU ----------------
template<int F>
__global__ __launch_bounds__(256) void gather_bn_relu(
    const int* __restrict__ off, const int* __restrict__ cnt,
    const int* __restrict__ esrc, const float* __restrict__ dinv,
    const unsigned short* __restrict__ hw, const float* __restrict__ bias,
    const float* __restrict__ g, const float* __restrict__ be,
    const float* __restrict__ m, const float* __restrict__ v,
    float* __restrict__ hout, int n)
{
    int node = blockIdx.x * (256 / F) + threadIdx.x / F;
    if (node >= n) return;
    int col = threadIdx.x % F;

    float S = bf2f(hw[(size_t)node * F + col]);   // self-loop term (hw' = hw*dinv)

    int beg = off[node];
    int num = cnt[node];
    int j = 0;
    for (; j + 3 < num; j += 4) {
        int s0 = esrc[beg + j + 0];
        int s1 = esrc[beg + j + 1];
        int s2 = esrc[beg + j + 2];
        int s3 = esrc[beg + j + 3];
        float h0 = bf2f(hw[(size_t)s0 * F + col]);
        float h1 = bf2f(hw[(size_t)s1 * F + col]);
        float h2 = bf2f(hw[(size_t)s2 * F + col]);
        float h3 = bf2f(hw[(size_t)s3 * F + col]);
        S += h0 + h1 + h2 + h3;
    }
    for (; j < num; ++j) {
        int s = esrc[beg + j];
        S += bf2f(hw[(size_t)s * F + col]);
    }

    float A = g[col] * rsqrtf(v[col] + BN_EPS);
    float y = A * (dinv[node] * S + bias[col] - m[col]) + be[col];
    hout[(size_t)node * F + col] = fmaxf(y, 0.0f);
}

// ---------------- final FC(16->8) + sigmoid ----------------
__global__ __launch_bounds__(256) void fc_sigmoid(
    const float* __restrict__ h, const float* __restrict__ W,
    const float* __restrict__ b, float* __restrict__ out, int n)
{
    __shared__ float Ws[16 * 8];
    __shared__ float bs[8];
    int tid = threadIdx.x;
    if (tid < 128) Ws[tid] = W[tid];
    if (tid < 8)   bs[tid] = b[tid];
    __syncthreads();

    int node = blockIdx.x * 256 + tid;
    if (node >= n) return;

    float hr[16];
    const float4* hp = reinterpret_cast<const float4*>(h + (size_t)node * 16);
#pragma unroll
    for (int q = 0; q < 4; ++q) {
        float4 t4 = hp[q];
        hr[q*4+0] = t4.x; hr[q*4+1] = t4.y; hr[q*4+2] = t4.z; hr[q*4+3] = t4.w;
    }
    float o[8];
#pragma unroll
    for (int c = 0; c < 8; ++c) o[c] = bs[c];
#pragma unroll
    for (int k = 0; k < 16; ++k) {
#pragma unroll
        for (int c = 0; c < 8; ++c) o[c] += hr[k] * Ws[k * 8 + c];
    }
    float4 o0, o1;
    o0.x = 1.0f / (1.0f + expf(-o[0]));
    o0.y = 1.0f / (1.0f + expf(-o[1]));
    o0.z = 1.0f / (1.0f + expf(-o[2]));
    o0.w = 1.0f / (1.0f + expf(-o[3]));
    o1.x = 1.0f / (1.0f + expf(-o[4]));
    o1.y = 1.0f / (1.0f + expf(-o[5]));
    o1.z = 1.0f / (1.0f + expf(-o[6]));
    o1.w = 1.0f / (1.0f + expf(-o[7]));
    float4* op = reinterpret_cast<float4*>(out + (size_t)node * 8);
    op[0] = o0;
    op[1] = o1;
}

// ---------------- launch ----------------
extern "C" void kernel_launch(void* const* d_in, const int* in_sizes, int n_in,
                              void* d_out, int out_size, void* d_ws, size_t ws_size,
                              hipStream_t stream) {
    const float* x   = (const float*)d_in[0];
    const int*   ei  = (const int*)  d_in[1];   // [2, E]: src row then dst row
    const float* W1  = (const float*)d_in[2];
    const float* b1  = (const float*)d_in[3];
    const float* g1  = (const float*)d_in[4];
    const float* be1 = (const float*)d_in[5];
    const float* m1  = (const float*)d_in[6];
    const float* v1  = (const float*)d_in[7];
    const float* W2  = (const float*)d_in[8];
    const float* b2  = (const float*)d_in[9];
    const float* g2  = (const float*)d_in[10];
    const float* be2 = (const float*)d_in[11];
    const float* m2  = (const float*)d_in[12];
    const float* v2  = (const float*)d_in[13];
    const float* W3  = (const float*)d_in[14];
    const float* b3  = (const float*)d_in[15];
    const float* g3  = (const float*)d_in[16];
    const float* be3 = (const float*)d_in[17];
    const float* m3  = (const float*)d_in[18];
    const float* v3  = (const float*)d_in[19];
    const float* fcW = (const float*)d_in[20];
    const float* fcb = (const float*)d_in[21];
    float* out = (float*)d_out;

    const int* src = ei;
    const int* dst = ei + NE;

    char* w = (char*)d_ws;
    float* dinv  = (float*)(w + 0);                 // N f32
    int*   cnt   = (int*)  (w + (512 << 10));       // N i32
    int*   off   = (int*)  (w + (1024 << 10));      // N i32
    int*   bhist = (int*)  (w + (1536 << 10));      // K_BKT i32
    int*   bbase = (int*)  (w + (1600 << 10));      // K_BKT i32
    int*   bcur  = (int*)  (w + (1664 << 10));      // K_BKT i32
    int*   staged= (int*)  (w + (2u << 20));        // E i32 = 6.4 MB
    int*   esrc  = (int*)  (w + (9u << 20));        // E i32 = 6.4 MB
    unsigned short* hw = (unsigned short*)(w + (16u << 20)); // N*64 bf16 = 12.8 MB
    float* H     = (float*)(w + (29u << 20));       // N*64 f32 = 25.6 MB

    float* h1 = H;
    float* h2 = H;
    float* h3 = H;

    // ---- CSR build: coarse hist -> scan -> partition -> place ----
    zero_i32<<<2, 256, 0, stream>>>(bhist, K_BKT);
    bucket_hist<<<256, 256, 0, stream>>>(dst, bhist, NE);
    scan_buckets<<<1, 256, 0, stream>>>(bhist, bbase, bcur);
    partition_edges<<<(NE + CH - 1) / CH, 256, 0, stream>>>(src, dst, bcur, staged, NE);
    place_edges<<<K_BKT, 256, 0, stream>>>(bbase, staged, esrc, off, cnt, dinv, NN, NE);

    // layer 1: 128 -> 64
    gemm_rows<128, 64><<<(NN + 15) / 16, 256, 0, stream>>>(x, W1, dinv, hw, NN);
    gather_bn_relu<64><<<(NN * 64 + 255) / 256, 256, 0, stream>>>(
        off, cnt, esrc, dinv, hw, b1, g1, be1, m1, v1, h1, NN);

    // layer 2: 64 -> 32
    gemm_rows<64, 32><<<(NN + 15) / 16, 256, 0, stream>>>(h1, W2, dinv, hw, NN);
    gather_bn_relu<32><<<(NN * 32 + 255) / 256, 256, 0, stream>>>(
        off, cnt, esrc, dinv, hw, b2, g2, be2, m2, v2, h2, NN);

    // layer 3: 32 -> 16
    gemm_rows<32, 16><<<(NN + 15) / 16, 256, 0, stream>>>(h2, W3, dinv, hw, NN);
    gather_bn_relu<16><<<(NN * 16 + 255) / 256, 256, 0, stream>>>(
        off, cnt, esrc, dinv, hw, b3, g3, be3, m3, v3, h3, NN);

    // FC + sigmoid
    fc_sigmoid<<<(NN + 255) / 256, 256, 0, stream>>>(h3, fcW, fcb, out, NN);
}

// Round 5
// 289.655 us; speedup vs baseline: 8.7152x; 1.0262x over previous
//
#include <hip/hip_runtime.h>
#include <math.h>

static constexpr int NN = 100000;   // nodes
static constexpr int NE = 1600000;  // edges
static constexpr float BN_EPS = 1e-5f;
static constexpr int K_BKT = (NN + 255) / 256;   // 391 coarse buckets (dst>>8)
static constexpr int CH = 8192;                  // edges per partition block

typedef __attribute__((ext_vector_type(8))) short bf16x8;
typedef __attribute__((ext_vector_type(4))) float f32x4;

// bf16 helpers (RNE pack, exact unpack)
__device__ __forceinline__ unsigned short f2bf(float f) {
    unsigned int u = __float_as_uint(f);
    u += 0x7fffu + ((u >> 16) & 1u);
    return (unsigned short)(u >> 16);
}
__device__ __forceinline__ float bf2f(unsigned short b) {
    return __uint_as_float(((unsigned int)b) << 16);
}

// ---------------- utility ----------------
__global__ void zero_i32(int* __restrict__ p, int n) {
    int i = blockIdx.x * blockDim.x + threadIdx.x;
    if (i < n) p[i] = 0;
}

// ---------------- coarse bucket histogram (LDS pre-aggregated) ----------------
__global__ __launch_bounds__(256) void bucket_hist(
    const int* __restrict__ dst, int* __restrict__ bhist, int e)
{
    __shared__ int h[K_BKT];
    for (int i = threadIdx.x; i < K_BKT; i += 256) h[i] = 0;
    __syncthreads();
    int stride = gridDim.x * 256;
    for (int i = blockIdx.x * 256 + threadIdx.x; i < e; i += stride)
        atomicAdd(&h[((unsigned)dst[i]) >> 8], 1);
    __syncthreads();
    for (int i = threadIdx.x; i < K_BKT; i += 256)
        if (h[i]) atomicAdd(&bhist[i], h[i]);
}

// ---------------- scan 391 bucket counts -> bases & cursors (1 block) --------
__global__ __launch_bounds__(256) void scan_buckets(
    const int* __restrict__ bhist, int* __restrict__ bbase, int* __restrict__ bcur)
{
    __shared__ int a[512];
    int tid = threadIdx.x;
    a[tid]       = (tid < K_BKT) ? bhist[tid] : 0;
    a[tid + 256] = (tid + 256 < K_BKT) ? bhist[tid + 256] : 0;
    __syncthreads();
    for (int d = 1; d < 512; d <<= 1) {
        int x0 = (tid >= d) ? a[tid - d] : 0;
        int i1 = tid + 256;
        int x1 = (i1 >= d) ? a[i1 - d] : 0;
        __syncthreads();
        a[tid] += x0;
        a[i1]  += x1;
        __syncthreads();
    }
    if (tid < K_BKT) {
        int ex = (tid == 0) ? 0 : a[tid - 1];
        bbase[tid] = ex; bcur[tid] = ex;
    }
    int i1 = tid + 256;
    if (i1 < K_BKT) {
        int ex = a[i1 - 1];
        bbase[i1] = ex; bcur[i1] = ex;
    }
}

// ---------------- partition: bucket-grouped staged writes (coalesced runs) ---
__global__ __launch_bounds__(256) void partition_edges(
    const int* __restrict__ src, const int* __restrict__ dst,
    int* __restrict__ bcur, int* __restrict__ staged, int e)
{
    __shared__ int s_out[CH];       // 32 KB
    __shared__ int cntL[512];       // counts -> inclusive scan
    __shared__ int gbase[K_BKT];
    __shared__ int curL[K_BKT];

    int tid = threadIdx.x;
    int c0 = blockIdx.x * CH;
    int cend = min(c0 + CH, e);

    for (int i = tid; i < 512; i += 256) cntL[i] = 0;
    __syncthreads();

    for (int i = c0 + tid; i < cend; i += 256)
        atomicAdd(&cntL[((unsigned)dst[i]) >> 8], 1);
    __syncthreads();

    for (int b = tid; b < K_BKT; b += 256) {
        int c = cntL[b];
        gbase[b] = (c > 0) ? atomicAdd(&bcur[b], c) : 0;
    }
    __syncthreads();

    for (int d = 1; d < 512; d <<= 1) {
        int x0 = (tid >= d) ? cntL[tid - d] : 0;
        int i1 = tid + 256;
        int x1 = (i1 >= d) ? cntL[i1 - d] : 0;
        __syncthreads();
        cntL[tid] += x0;
        cntL[i1]  += x1;
        __syncthreads();
    }
    for (int b = tid; b < K_BKT; b += 256)
        curL[b] = (b == 0) ? 0 : cntL[b - 1];
    __syncthreads();

    for (int i = c0 + tid; i < cend; i += 256) {
        int s = src[i];
        int d = dst[i];
        int b = ((unsigned)d) >> 8;
        int r = atomicAdd(&curL[b], 1);
        s_out[r] = s | ((d & 255) << 24);
    }
    __syncthreads();

    int wave = tid >> 6, lane = tid & 63;
    for (int b = wave; b < K_BKT; b += 4) {
        int lo = (b == 0) ? 0 : cntL[b - 1];
        int hi = cntL[b];
        int gb = gbase[b];
        for (int i = lo + lane; i < hi; i += 64)
            staged[gb + (i - lo)] = s_out[i];
    }
}

// ---------------- place: per-bucket CSR finalize (XCD-local writes) ----------
__global__ __launch_bounds__(256) void place_edges(
    const int* __restrict__ bbase, const int* __restrict__ staged,
    int* __restrict__ esrc, int* __restrict__ off, int* __restrict__ cnt,
    float* __restrict__ dinv, int n, int e)
{
    __shared__ int cntL[256];
    __shared__ int scn[256];
    __shared__ int curL[256];
    int b = blockIdx.x;
    int tid = threadIdx.x;
    int node0 = b << 8;
    int nN = min(256, n - node0);
    int beg = bbase[b];
    int end = (b == (int)gridDim.x - 1) ? e : bbase[b + 1];

    cntL[tid] = 0;
    __syncthreads();
    for (int i = beg + tid; i < end; i += 256)
        atomicAdd(&cntL[((unsigned)staged[i]) >> 24], 1);
    __syncthreads();
    scn[tid] = cntL[tid];
    __syncthreads();
    for (int d = 1; d < 256; d <<= 1) {
        int x = (tid >= d) ? scn[tid - d] : 0;
        __syncthreads();
        scn[tid] += x;
        __syncthreads();
    }
    int lofs = (tid == 0) ? 0 : scn[tid - 1];
    if (tid < nN) {
        int node = node0 + tid;
        off[node] = beg + lofs;
        cnt[node] = cntL[tid];
        dinv[node] = rsqrtf((float)cntL[tid] + 1.0f);
    }
    curL[tid] = beg + lofs;
    __syncthreads();
    for (int i = beg + tid; i < end; i += 256) {
        int u = staged[i];
        int pos = atomicAdd(&curL[((unsigned)u) >> 24], 1);
        esrc[pos] = u & 0x00FFFFFF;
    }
}

// ---------------- W prep: Wt[FOUT][3K] bf16 = [W_hi ; W_hi ; W_lo] ----------
template<int K, int FOUT>
__global__ __launch_bounds__(256) void prep_w(
    const float* __restrict__ W, unsigned short* __restrict__ wt)
{
    int t = blockIdx.x * 256 + threadIdx.x;
    constexpr int QK = K / 4;
    if (t >= FOUT * QK) return;
    int c = t / QK;
    int q = t % QK;
    ushort4 hi, lo;
    float v0 = W[(q * 4 + 0) * FOUT + c];
    float v1 = W[(q * 4 + 1) * FOUT + c];
    float v2 = W[(q * 4 + 2) * FOUT + c];
    float v3 = W[(q * 4 + 3) * FOUT + c];
    hi.x = f2bf(v0); lo.x = f2bf(v0 - bf2f(hi.x));
    hi.y = f2bf(v1); lo.y = f2bf(v1 - bf2f(hi.y));
    hi.z = f2bf(v2); lo.z = f2bf(v2 - bf2f(hi.z));
    hi.w = f2bf(v3); lo.w = f2bf(v3 - bf2f(hi.w));
    unsigned short* row = wt + (size_t)c * 3 * K;
    *reinterpret_cast<ushort4*>(row + q * 4)         = hi;
    *reinterpret_cast<ushort4*>(row + K + q * 4)     = hi;
    *reinterpret_cast<ushort4*>(row + 2 * K + q * 4) = lo;
}

// ---------------- MFMA GEMM: hw' = (h @ W) * dinv, stored bf16 ----------------
// Split-precision: A' = [A_hi | A_lo | A_hi], Wt = [W_hi ; W_hi ; W_lo] -> exact fp32-grade.
// 64 rows/block, 4 waves x 16 rows. A in LDS (padded), B-frags straight from global Wt.
template<int K, int FOUT>
__global__ __launch_bounds__(256) void gemm_mfma(
    const float* __restrict__ h, const unsigned short* __restrict__ wt,
    const float* __restrict__ dinv, unsigned short* __restrict__ hw, int n)
{
    constexpr int PAD = 8;
    constexpr int LDA = 2 * K + PAD;       // bf16 elems per LDS row (stride%128B==16 -> conflict-free)
    constexpr int CT  = FOUT / 16;         // 16-col tiles
    constexpr int KS  = (3 * K) / 32;      // k-steps
    __shared__ unsigned short As[64 * LDA];

    const int tid  = threadIdx.x;
    const int row0 = blockIdx.x * 64;

    // ---- stage A: hi/lo split ----
    constexpr int QK = K / 4;
    for (int i = tid; i < 64 * QK; i += 256) {
        int r = i / QK;
        int q = i % QK;
        int g = row0 + r;
        float4 v;
        if (g < n) v = *reinterpret_cast<const float4*>(h + (size_t)g * K + q * 4);
        else       v = make_float4(0.f, 0.f, 0.f, 0.f);
        ushort4 hi, lo;
        hi.x = f2bf(v.x); lo.x = f2bf(v.x - bf2f(hi.x));
        hi.y = f2bf(v.y); lo.y = f2bf(v.y - bf2f(hi.y));
        hi.z = f2bf(v.z); lo.z = f2bf(v.z - bf2f(hi.z));
        hi.w = f2bf(v.w); lo.w = f2bf(v.w - bf2f(hi.w));
        *reinterpret_cast<ushort4*>(&As[r * LDA + q * 4])     = hi;
        *reinterpret_cast<ushort4*>(&As[r * LDA + K + q * 4]) = lo;
    }
    __syncthreads();

    const int wave = tid >> 6;
    const int lane = tid & 63;
    const int l15  = lane & 15;
    const int kgrp = (lane >> 4) * 8;
    const int arow = wave * 16 + l15;

    f32x4 acc[CT];
#pragma unroll
    for (int ct = 0; ct < CT; ++ct) acc[ct] = (f32x4){0.f, 0.f, 0.f, 0.f};

#pragma unroll
    for (int ks = 0; ks < KS; ++ks) {
        int kp = ks * 32 + kgrp;                     // k' in [0, 3K)
        int ka = (kp >= 2 * K) ? kp - 2 * K : kp;    // A' region fold
        bf16x8 a = *reinterpret_cast<const bf16x8*>(&As[arow * LDA + ka]);
#pragma unroll
        for (int ct = 0; ct < CT; ++ct) {
            int col = ct * 16 + l15;
            bf16x8 b = *reinterpret_cast<const bf16x8*>(&wt[(size_t)col * 3 * K + kp]);
            acc[ct] = __builtin_amdgcn_mfma_f32_16x16x32_bf16(a, b, acc[ct], 0, 0, 0);
        }
    }

    // ---- epilogue: scale by dinv, pack bf16 ----
    const int rbase = wave * 16 + (lane >> 4) * 4;
    float dv[4];
#pragma unroll
    for (int j = 0; j < 4; ++j) {
        int g = row0 + rbase + j;
        dv[j] = (g < n) ? dinv[g] : 0.f;
    }
#pragma unroll
    for (int ct = 0; ct < CT; ++ct) {
#pragma unroll
        for (int j = 0; j < 4; ++j) {
            int g = row0 + rbase + j;
            if (g < n) hw[(size_t)g * FOUT + ct * 16 + l15] = f2bf(acc[ct][j] * dv[j]);
        }
    }
}

// ---------------- gather + self-loop + bias + BN + ReLU ----------------
template<int F>
__global__ __launch_bounds__(256) void gather_bn_relu(
    const int* __restrict__ off, const int* __restrict__ cnt,
    const int* __restrict__ esrc, const float* __restrict__ dinv,
    const unsigned short* __restrict__ hw, const float* __restrict__ bias,
    const float* __restrict__ g, const float* __restrict__ be,
    const float* __restrict__ m, const float* __restrict__ v,
    float* __restrict__ hout, int n)
{
    int node = blockIdx.x * (256 / F) + threadIdx.x / F;
    if (node >= n) return;
    int col = threadIdx.x % F;

    float S = bf2f(hw[(size_t)node * F + col]);   // self-loop (hw' = hw*dinv)

    int beg = off[node];
    int num = cnt[node];
    int j = 0;
    for (; j + 3 < num; j += 4) {
        int s0 = esrc[beg + j + 0];
        int s1 = esrc[beg + j + 1];
        int s2 = esrc[beg + j + 2];
        int s3 = esrc[beg + j + 3];
        float h0 = bf2f(hw[(size_t)s0 * F + col]);
        float h1 = bf2f(hw[(size_t)s1 * F + col]);
        float h2 = bf2f(hw[(size_t)s2 * F + col]);
        float h3 = bf2f(hw[(size_t)s3 * F + col]);
        S += h0 + h1 + h2 + h3;
    }
    for (; j < num; ++j) {
        int s = esrc[beg + j];
        S += bf2f(hw[(size_t)s * F + col]);
    }

    float A = g[col] * rsqrtf(v[col] + BN_EPS);
    float y = A * (dinv[node] * S + bias[col] - m[col]) + be[col];
    hout[(size_t)node * F + col] = fmaxf(y, 0.0f);
}

// ---------------- final FC(16->8) + sigmoid ----------------
__global__ __launch_bounds__(256) void fc_sigmoid(
    const float* __restrict__ h, const float* __restrict__ W,
    const float* __restrict__ b, float* __restrict__ out, int n)
{
    __shared__ float Ws[16 * 8];
    __shared__ float bs[8];
    int tid = threadIdx.x;
    if (tid < 128) Ws[tid] = W[tid];
    if (tid < 8)   bs[tid] = b[tid];
    __syncthreads();

    int node = blockIdx.x * 256 + tid;
    if (node >= n) return;

    float hr[16];
    const float4* hp = reinterpret_cast<const float4*>(h + (size_t)node * 16);
#pragma unroll
    for (int q = 0; q < 4; ++q) {
        float4 t4 = hp[q];
        hr[q*4+0] = t4.x; hr[q*4+1] = t4.y; hr[q*4+2] = t4.z; hr[q*4+3] = t4.w;
    }
    float o[8];
#pragma unroll
    for (int c = 0; c < 8; ++c) o[c] = bs[c];
#pragma unroll
    for (int k = 0; k < 16; ++k) {
#pragma unroll
        for (int c = 0; c < 8; ++c) o[c] += hr[k] * Ws[k * 8 + c];
    }
    float4 o0, o1;
    o0.x = 1.0f / (1.0f + expf(-o[0]));
    o0.y = 1.0f / (1.0f + expf(-o[1]));
    o0.z = 1.0f / (1.0f + expf(-o[2]));
    o0.w = 1.0f / (1.0f + expf(-o[3]));
    o1.x = 1.0f / (1.0f + expf(-o[4]));
    o1.y = 1.0f / (1.0f + expf(-o[5]));
    o1.z = 1.0f / (1.0f + expf(-o[6]));
    o1.w = 1.0f / (1.0f + expf(-o[7]));
    float4* op = reinterpret_cast<float4*>(out + (size_t)node * 8);
    op[0] = o0;
    op[1] = o1;
}

// ---------------- launch ----------------
extern "C" void kernel_launch(void* const* d_in, const int* in_sizes, int n_in,
                              void* d_out, int out_size, void* d_ws, size_t ws_size,
                              hipStream_t stream) {
    const float* x   = (const float*)d_in[0];
    const int*   ei  = (const int*)  d_in[1];   // [2, E]: src row then dst row
    const float* W1  = (const float*)d_in[2];
    const float* b1  = (const float*)d_in[3];
    const float* g1  = (const float*)d_in[4];
    const float* be1 = (const float*)d_in[5];
    const float* m1  = (const float*)d_in[6];
    const float* v1  = (const float*)d_in[7];
    const float* W2  = (const float*)d_in[8];
    const float* b2  = (const float*)d_in[9];
    const float* g2  = (const float*)d_in[10];
    const float* be2 = (const float*)d_in[11];
    const float* m2  = (const float*)d_in[12];
    const float* v2  = (const float*)d_in[13];
    const float* W3  = (const float*)d_in[14];
    const float* b3  = (const float*)d_in[15];
    const float* g3  = (const float*)d_in[16];
    const float* be3 = (const float*)d_in[17];
    const float* m3  = (const float*)d_in[18];
    const float* v3  = (const float*)d_in[19];
    const float* fcW = (const float*)d_in[20];
    const float* fcb = (const float*)d_in[21];
    float* out = (float*)d_out;

    const int* src = ei;
    const int* dst = ei + NE;

    char* w = (char*)d_ws;
    float* dinv  = (float*)(w + 0);                 // N f32
    int*   cnt   = (int*)  (w + (512 << 10));       // N i32
    int*   off   = (int*)  (w + (1024 << 10));      // N i32
    int*   bhist = (int*)  (w + (1536 << 10));      // K_BKT i32
    int*   bbase = (int*)  (w + (1600 << 10));      // K_BKT i32
    int*   bcur  = (int*)  (w + (1664 << 10));      // K_BKT i32
    int*   staged= (int*)  (w + (2u << 20));        // E i32 = 6.4 MB (ends 8.1 MB)
    unsigned short* wt1 = (unsigned short*)(w + (8600u << 10)); // 64*384 u16 = 48 KB
    unsigned short* wt2 = wt1 + 64 * 384;                        // 32*192 u16 = 12 KB
    unsigned short* wt3 = wt2 + 32 * 192;                        // 16*96  u16 = 3 KB
    int*   esrc  = (int*)  (w + (9u << 20));        // E i32 = 6.4 MB
    unsigned short* hw = (unsigned short*)(w + (16u << 20)); // N*64 bf16 = 12.8 MB
    float* H     = (float*)(w + (29u << 20));       // N*64 f32 = 25.6 MB

    float* h1 = H;
    float* h2 = H;
    float* h3 = H;

    // ---- W prep (tiny; independent of CSR) ----
    prep_w<128, 64><<<(64 * 32 + 255) / 256, 256, 0, stream>>>(W1, wt1);
    prep_w<64, 32><<<(32 * 16 + 255) / 256, 256, 0, stream>>>(W2, wt2);
    prep_w<32, 16><<<(16 * 8 + 255) / 256, 256, 0, stream>>>(W3, wt3);

    // ---- CSR build: coarse hist -> scan -> partition -> place ----
    zero_i32<<<2, 256, 0, stream>>>(bhist, K_BKT);
    bucket_hist<<<256, 256, 0, stream>>>(dst, bhist, NE);
    scan_buckets<<<1, 256, 0, stream>>>(bhist, bbase, bcur);
    partition_edges<<<(NE + CH - 1) / CH, 256, 0, stream>>>(src, dst, bcur, staged, NE);
    place_edges<<<K_BKT, 256, 0, stream>>>(bbase, staged, esrc, off, cnt, dinv, NN, NE);

    // layer 1: 128 -> 64
    gemm_mfma<128, 64><<<(NN + 63) / 64, 256, 0, stream>>>(x, wt1, dinv, hw, NN);
    gather_bn_relu<64><<<(NN * 64 + 255) / 256, 256, 0, stream>>>(
        off, cnt, esrc, dinv, hw, b1, g1, be1, m1, v1, h1, NN);

    // layer 2: 64 -> 32
    gemm_mfma<64, 32><<<(NN + 63) / 64, 256, 0, stream>>>(h1, wt2, dinv, hw, NN);
    gather_bn_relu<32><<<(NN * 32 + 255) / 256, 256, 0, stream>>>(
        off, cnt, esrc, dinv, hw, b2, g2, be2, m2, v2, h2, NN);

    // layer 3: 32 -> 16
    gemm_mfma<32, 16><<<(NN + 63) / 64, 256, 0, stream>>>(h2, wt3, dinv, hw, NN);
    gather_bn_relu<16><<<(NN * 16 + 255) / 256, 256, 0, stream>>>(
        off, cnt, esrc, dinv, hw, b3, g3, be3, m3, v3, h3, NN);

    // FC + sigmoid
    fc_sigmoid<<<(NN + 255) / 256, 256, 0, stream>>>(h3, fcW, fcb, out, NN);
}